// Round 1
// 192.772 us; speedup vs baseline: 1.0006x; 1.0006x over previous
//
#include <hip/hip_runtime.h>

// Problem constants
#define BN   4
#define NN   128
#define INF  256
#define EF   128
#define OUTF 128
#define EPSF 1e-5f
#define NEGF -998244352.0f   // bf16(1e9); matches the bf16-rounded np reference

typedef __attribute__((ext_vector_type(8))) short short8;
typedef __attribute__((ext_vector_type(4))) float f32x4;

#define MFMA16(a, b, c) __builtin_amdgcn_mfma_f32_16x16x32_bf16(a, b, c, 0, 0, 0)

__device__ __forceinline__ unsigned short f2bf(float f) {
    unsigned u = __float_as_uint(f);
    u += 0x7fffu + ((u >> 16) & 1u);
    return (unsigned short)(u >> 16);
}
__device__ __forceinline__ unsigned pack2(float a, float b) {
    return (unsigned)f2bf(a) | ((unsigned)f2bf(b) << 16);
}

// ---- workspace layout (float offsets) ----
constexpr size_t TRI1 = 0;            // B*N*8   tri_1 (masked)  [now folded into E1T; kept for safety]
constexpr size_t TRI2 = 4096;
constexpr size_t TRI3 = 8192;
constexpr size_t MSG1 = 12288;        // B*N*128 msg_1 (masked)
constexpr size_t MSG2 = 77824;
constexpr size_t ZWU1 = 143360;
constexpr size_t TRIG = 208896;       // B*8
constexpr size_t MSGG = 209920;       // B*128
constexpr size_t E1T  = 210944;       // B*N*N*8  fp32 [b][j][i][c]  (tri_e1 + tri_1 folded)
constexpr size_t E2T  = 735232;       // B*N*N*8  fp32 [b][k][i][c]
constexpr size_t E3N  = 1259520;      // B*N*N*8  fp32 [b][j][k][c]
constexpr size_t PM0  = 1783808;      // 2 * B*N*128 partial colmax (pair halves)
constexpr size_t PREPF = 1914880;     // bf16 prepped weights (ushort region)

// prep (ushort units), MFMA-fragment order:
// ((ks*8 + t)*64 + lane)*8 + jj == W^T[16t + (lane&15)][ks*32 + (lane>>4)*8 + jj]
constexpr int W1T_OFF  = 0;
constexpr int W2T_OFF  = 16384;
constexpr int WMET_OFF = 32768;

// ---- output layout (float offsets): ret, msgs, tri_msgs ----
constexpr size_t O_RET = 0;
constexpr size_t O_MSG = 65536;
constexpr size_t O_TRI = 131072;

__device__ __forceinline__ int detect_int(const void* mask) {
    const unsigned char* m = (const unsigned char*)mask;
    return (m[1] | m[2] | m[3]) == 0 ? 1 : 0;
}
__device__ __forceinline__ bool rdbool(const void* p, size_t idx, int isInt) {
    if (isInt) return ((const int*)p)[idx] != 0;
    return ((const unsigned char*)p)[idx] != 0;
}

// ============================================================
// K1: tri-e projection (0..511, full 128-row blocks) + z proj (512..1023)
//     + graph (1024..1027) + weight prep (1028..1219).  256 thr.
// NOTE: (256,4) NOT (256,8) — the tighter bound caps VGPR at 32 and forces
// scratch spills of bfrag (measured r11: VGPR 32, WRITE_SIZE 2.2x, 2x slower).
// NEW: tri_1 (masked z@Wt1 row) is computed per-block and FOLDED into E1T,
// so k_main's triplet stage is a pure copy.
// ============================================================
__global__ __launch_bounds__(256, 4) void k_pre(
    const float* __restrict__ z, const float* __restrict__ e, const void* __restrict__ mask,
    const float* __restrict__ Wt1, const float* __restrict__ Wt2, const float* __restrict__ Wt3,
    const float* __restrict__ Wm1, const float* __restrict__ Wm2, const float* __restrict__ WU1,
    const float* __restrict__ g, const float* __restrict__ Wg, const float* __restrict__ Wmg,
    const float* __restrict__ W1, const float* __restrict__ W2, const float* __restrict__ Wme,
    const float* __restrict__ We1, const float* __restrict__ We2, const float* __restrict__ We3,
    float* __restrict__ ws, unsigned short* __restrict__ prep)
{
    int bx = blockIdx.x, tid = threadIdx.x;
    __shared__ __align__(16) unsigned char smem[128 * 136 * 2];

    if (bx < 512) {
        // ---------- tri-e projection: block = one (b,i) ----------
        unsigned short* Ab = (unsigned short*)smem;
        int bi = bx;
        int b = bi >> 7, i = bi & 127;
        int lane = tid & 63, w = tid >> 6, q = lane >> 4, n = lane & 15;
        {
            int half = lane >> 5, c4 = (lane & 31) * 4;
            #pragma unroll
            for (int it = 0; it < 16; it++) {
                int row = 32 * w + 2 * it + half;
                float4 v = *(const float4*)(e + (size_t)bi * 16384 + (size_t)row * 128 + c4);
                unsigned* dst = (unsigned*)&Ab[row * 136 + c4];
                dst[0] = pack2(v.x, v.y);
                dst[1] = pack2(v.z, v.w);
            }
        }
        // t1 row for node i: masked z[b,i,:]@Wt1, per-wave redundant.
        // After the xor-reduce every lane holds t1[lane&7]; the E1T-writing
        // lanes have n<8 so lane&7 == n — exactly the channel they write.
        float t1v;
        {
            int c = lane & 7, kk = lane >> 3;   // kk in 0..7, 32-k chunks
            const float* zr = z + (size_t)bi * INF;
            float s = 0.f;
            #pragma unroll
            for (int m = 0; m < 32; m++) s = fmaf(zr[kk * 32 + m], Wt1[(kk * 32 + m) * 8 + c], s);
            s += __shfl_xor(s, 8, 64);
            s += __shfl_xor(s, 16, 64);
            s += __shfl_xor(s, 32, 64);
            int isInt = detect_int(mask);
            t1v = rdbool(mask, bi, isInt) ? s : 0.f;
        }
        // gather packed-We B fragments (cols: We1|We2|We3|0), L1-hot 4KB arrays
        short8 bfrag[4][2];
        {
            #pragma unroll
            for (int t = 0; t < 2; t++) {
                int col = 16 * t + n;
                const float* Wsel = (col < 8) ? We1 : (col < 16 ? We2 : We3);
                int csel = col & 7;
                float mval = (col < 24) ? 1.f : 0.f;
                #pragma unroll
                for (int ks = 0; ks < 4; ks++) {
                    union { short8 s; unsigned short u[8]; } tmp;
                    #pragma unroll
                    for (int jj = 0; jj < 8; jj++) {
                        int k = ks * 32 + q * 8 + jj;
                        tmp.u[jj] = f2bf(Wsel[k * 8 + csel] * mval);
                    }
                    bfrag[ks][t] = tmp.s;
                }
            }
        }
        __builtin_amdgcn_wave_barrier();

        f32x4 ac2[2][2];
        #pragma unroll
        for (int rt = 0; rt < 2; rt++)
            #pragma unroll
            for (int t = 0; t < 2; t++) ac2[rt][t] = 0.f;
        #pragma unroll
        for (int ks = 0; ks < 4; ks++) {
            int k0 = ks * 32 + q * 8;
            short8 a0 = *(const short8*)&Ab[(32 * w + n) * 136 + k0];
            short8 a1 = *(const short8*)&Ab[(32 * w + 16 + n) * 136 + k0];
            #pragma unroll
            for (int t = 0; t < 2; t++) {
                ac2[0][t] = MFMA16(a0, bfrag[ks][t], ac2[0][t]);
                ac2[1][t] = MFMA16(a1, bfrag[ks][t], ac2[1][t]);
            }
        }
        #pragma unroll
        for (int rt = 0; rt < 2; rt++)
            #pragma unroll
            for (int reg = 0; reg < 4; reg++) {
                int row = 32 * w + 16 * rt + 4 * q + reg;
                float v0 = ac2[rt][0][reg];
                if (n < 8) ws[E1T + ((size_t)(b * 128 + row) * 128 + i) * 8 + n] = v0 + t1v;
                else       ws[E2T + ((size_t)(b * 128 + row) * 128 + i) * 8 + (n - 8)] = v0;
                if (n < 8) ws[E3N + ((size_t)bi * 128 + row) * 8 + n] = ac2[rt][1][reg];
            }
        return;
    }
    if (bx < 1024) {
        // ---------- z-row projections (2-way split accumulators for ILP) ----------
        int bn = bx - 512;
        int isInt = detect_int(mask);
        float* zr = (float*)smem;
        zr[tid] = z[(size_t)bn * INF + tid];
        __syncthreads();
        float mk = rdbool(mask, bn, isInt) ? 1.f : 0.f;
        for (int idx = tid; idx < 408; idx += 256) {
            const float* W; int c; size_t dst; int width; bool msk;
            if (idx < 8)        { W = Wt1; c = idx;       dst = TRI1 + (size_t)bn * 8;   width = 8;   msk = true;  }
            else if (idx < 16)  { W = Wt2; c = idx - 8;   dst = TRI2 + (size_t)bn * 8;   width = 8;   msk = true;  }
            else if (idx < 24)  { W = Wt3; c = idx - 16;  dst = TRI3 + (size_t)bn * 8;   width = 8;   msk = true;  }
            else if (idx < 152) { W = Wm1; c = idx - 24;  dst = MSG1 + (size_t)bn * 128; width = 128; msk = true;  }
            else if (idx < 280) { W = Wm2; c = idx - 152; dst = MSG2 + (size_t)bn * 128; width = 128; msk = true;  }
            else                { W = WU1; c = idx - 280; dst = ZWU1 + (size_t)bn * 128; width = 128; msk = false; }
            float a0 = 0.f, a1 = 0.f;
            #pragma unroll 8
            for (int k = 0; k < INF; k += 2) {
                a0 += zr[k] * W[k * width + c];
                a1 += zr[k + 1] * W[(k + 1) * width + c];
            }
            float acc = a0 + a1;
            ws[dst + c] = msk ? acc * mk : acc;
        }
        return;
    }
    if (bx < 1028) {
        // ---------- graph_fts projections ----------
        int b = bx - 1024;
        float* gr = (float*)smem;
        if (tid < 128) gr[tid] = g[b * 128 + tid];
        __syncthreads();
        if (tid < 8) {
            float a = 0.f;
            for (int k = 0; k < 128; k++) a += gr[k] * Wg[k * 8 + tid];
            ws[TRIG + b * 8 + tid] = a;
        } else if (tid >= 128) {
            int c = tid - 128;
            float a = 0.f;
            for (int k = 0; k < 128; k++) a += gr[k] * Wmg[k * 128 + c];
            ws[MSGG + b * 128 + c] = a;
        }
        return;
    }
    // ---------- weight prep (fragment-order), W1/W2/Wme only ----------
    {
        int idx = (bx - 1028) * 256 + tid;   // < 49152
        const float* W = (idx < 16384) ? W1 : (idx < 32768 ? W2 : Wme);
        int local = idx & 16383;
        int f = local >> 3, jj = local & 7;
        int lane = f & 63, fg = f >> 6;
        int t = fg & 7, ks = fg >> 3;
        int n = lane & 15, q = lane >> 4;
        int row = 16 * t + n;
        int k = ks * 32 + q * 8 + jj;
        prep[idx] = f2bf(W[k * 128 + row]);
    }
}

// ============================================================
// K2: bx<256 triplet pooling (redesigned), bx>=256 pair-MLP HALF blocks.
// grid 1280, block 256, LDS 19.5KB -> up to 8 blocks/CU by LDS.
//
// Triplet redesign: 16x16 (j,k) tile. Waves split (i-half x channel-half);
// each lane register-blocks 2x2 outputs (lane -> 8x8, outputs +0/+8), so
// LDS bytes per max-step drop 8B -> 4B (inner traffic 2MB -> 1MB/block).
// Staging is WAVE-PRIVATE (no __syncthreads in the i loop); mask bits live
// in SGPRs via __ballot. LDS stride 36 words makes the 8-distinct-address
// b128 reads tile all 32 banks (conflict-free). Partials merged into
// 'pooled' with 2 sequenced rounds (3 syncthreads total).
//
// Pair split: each (b,j) becomes two 64-row half blocks (LN is per-row,
// the adj-max is associative); halves write partial colmax to ws[PM0],
// k_final combines.
// ============================================================
__global__ __launch_bounds__(256, 4) void k_main(
    const float* __restrict__ e, const void* __restrict__ mask, const void* __restrict__ adj,
    const float* __restrict__ ln1s, const float* __restrict__ ln1o,
    const float* __restrict__ ln2s, const float* __restrict__ ln2o,
    const unsigned short* __restrict__ prep, const float* __restrict__ WU3,
    float* __restrict__ ws, float* __restrict__ out)
{
    int bx = blockIdx.x, tid = threadIdx.x;
    __shared__ __align__(16) unsigned char smem[64 * 136 * 2 + 2048];   // 19456 B
    int lane = tid & 63, w = tid >> 6, q = lane >> 4, n = lane & 15;
    int isInt = detect_int(mask);

    if (bx < 256) {
        // ================= triplet max-plus pooling =================
        int g = bx;
        int j0 = ((g >> 3) & 7) * 16, k0 = (g & 7) * 16, b = g >> 6;
        int wi = w >> 1, wc = w & 1;          // i-half, channel-half
        int tj = lane >> 3, tk = lane & 7;    // 8x8 lanes; outputs (tj,tj+8)x(tk,tk+8)
        int col4 = (tid & 31) * 4, rowgrp = tid >> 5;

        // mask bits for this wave's 64-i range (uniform -> SGPR pair)
        unsigned long long mball = __ballot(rdbool(mask, (size_t)b * 128 + wi * 64 + lane, isInt));

        // wave-private staging: P[16][8ii][4c]+pad and Q, stride 36 words
        float* Pb = (float*)smem + w * 1152;
        float* Qb = Pb + 576;

        f32x4 aM[2][2], aU[2][2];
        #pragma unroll
        for (int jj = 0; jj < 2; jj++)
            #pragma unroll
            for (int kk = 0; kk < 2; kk++) { aM[jj][kk] = NEGF; aU[jj][kk] = NEGF; }

        for (int ch = 0; ch < 8; ch++) {
            int ibase = wi * 64 + ch * 8;
            // stage this wave's 8-i slice of its channel half (pure copy; t1 folded)
            #pragma unroll
            for (int r = 0; r < 2; r++) {
                int f = r * 64 + lane;
                int jr = f >> 3, ii = f & 7;
                f32x4 pv = *(const f32x4*)(ws + E1T + (size_t)(b * 128 + j0 + jr) * 1024 + (ibase + ii) * 8 + wc * 4);
                f32x4 qv = *(const f32x4*)(ws + E2T + (size_t)(b * 128 + k0 + jr) * 1024 + (ibase + ii) * 8 + wc * 4);
                *(f32x4*)(Pb + jr * 36 + ii * 4) = pv;
                *(f32x4*)(Qb + jr * 36 + ii * 4) = qv;
            }
            __builtin_amdgcn_wave_barrier();
            #pragma unroll
            for (int ii = 0; ii < 8; ii++) {
                f32x4 p0 = *(const f32x4*)(Pb + tj * 36 + ii * 4);
                f32x4 p1 = *(const f32x4*)(Pb + (tj + 8) * 36 + ii * 4);
                f32x4 q0 = *(const f32x4*)(Qb + tk * 36 + ii * 4);
                f32x4 q1 = *(const f32x4*)(Qb + (tk + 8) * 36 + ii * 4);
                f32x4 v00 = p0 + q0, v01 = p0 + q1, v10 = p1 + q0, v11 = p1 + q1;
                if ((mball >> (ch * 8 + ii)) & 1) {
                    aM[0][0] = __builtin_elementwise_max(aM[0][0], v00);
                    aM[0][1] = __builtin_elementwise_max(aM[0][1], v01);
                    aM[1][0] = __builtin_elementwise_max(aM[1][0], v10);
                    aM[1][1] = __builtin_elementwise_max(aM[1][1], v11);
                } else {
                    aU[0][0] = __builtin_elementwise_max(aU[0][0], v00);
                    aU[0][1] = __builtin_elementwise_max(aU[0][1], v01);
                    aU[1][0] = __builtin_elementwise_max(aU[1][0], v10);
                    aU[1][1] = __builtin_elementwise_max(aU[1][1], v11);
                }
            }
        }
        // mask-select (mj|mk per output); write into aM in place
        {
            bool mj[2], mk2[2];
            mj[0]  = rdbool(mask, (size_t)b * 128 + j0 + tj, isInt);
            mj[1]  = rdbool(mask, (size_t)b * 128 + j0 + tj + 8, isInt);
            mk2[0] = rdbool(mask, (size_t)b * 128 + k0 + tk, isInt);
            mk2[1] = rdbool(mask, (size_t)b * 128 + k0 + tk + 8, isInt);
            #pragma unroll
            for (int jj = 0; jj < 2; jj++)
                #pragma unroll
                for (int kk = 0; kk < 2; kk++)
                    if (mj[jj] | mk2[kk])
                        aM[jj][kk] = __builtin_elementwise_max(aM[jj][kk], aU[jj][kk]);
        }
        __syncthreads();   // all staging reads done; alias staging region as 'pooled'
        float* pooled = (float*)smem;   // [8][260] c-major
        float4 wvr[8];
        #pragma unroll
        for (int c = 0; c < 8; c++) wvr[c] = *(const float4*)(WU3 + c * 128 + col4);

        if (wi == 0) {
            #pragma unroll
            for (int jj = 0; jj < 2; jj++)
                #pragma unroll
                for (int kk = 0; kk < 2; kk++) {
                    int p = (tj + 8 * jj) * 16 + (tk + 8 * kk);
                    #pragma unroll
                    for (int cc = 0; cc < 4; cc++)
                        pooled[(wc * 4 + cc) * 260 + p] = aM[jj][kk][cc];
                }
        }
        __syncthreads();
        if (wi == 1) {
            const float* tg = ws + TRIG + (size_t)b * 8 + wc * 4;
            #pragma unroll
            for (int jj = 0; jj < 2; jj++)
                #pragma unroll
                for (int kk = 0; kk < 2; kk++) {
                    int jv = j0 + tj + 8 * jj, kv = k0 + tk + 8 * kk;
                    const float* t2 = ws + TRI2 + (size_t)(b * 128 + jv) * 8 + wc * 4;
                    const float* t3 = ws + TRI3 + (size_t)(b * 128 + kv) * 8 + wc * 4;
                    const float* e3 = ws + E3N + ((size_t)(b * 128 + jv) * 128 + kv) * 8 + wc * 4;
                    int p = (tj + 8 * jj) * 16 + (tk + 8 * kk);
                    #pragma unroll
                    for (int cc = 0; cc < 4; cc++) {
                        int idx = (wc * 4 + cc) * 260 + p;
                        pooled[idx] = fmaxf(pooled[idx], aM[jj][kk][cc]) + t2[cc] + t3[cc] + e3[cc] + tg[cc];
                    }
                }
        }
        __syncthreads();
        // epilogue: relu(pooled @ WU3); pooled reads broadcast, no LDS weights
        #pragma unroll
        for (int pass = 0; pass < 32; pass++) {
            int p = pass * 8 + rowgrp;
            float4 s = { 0.f, 0.f, 0.f, 0.f };
            #pragma unroll
            for (int c = 0; c < 8; c++) {
                float pv = pooled[c * 260 + p];
                s.x += pv * wvr[c].x; s.y += pv * wvr[c].y;
                s.z += pv * wvr[c].z; s.w += pv * wvr[c].w;
            }
            s.x = fmaxf(s.x, 0.f); s.y = fmaxf(s.y, 0.f);
            s.z = fmaxf(s.z, 0.f); s.w = fmaxf(s.w, 0.f);
            int pj = p >> 4, pk = p & 15;
            *(float4*)(out + O_TRI + ((size_t)(b * 128 + j0 + pj) * 128 + (k0 + pk)) * 128 + col4) = s;
        }
        return;
    }

    // ================= pair MLP half: block = (b, j, hb) 64 rows =================
    unsigned short* Ab = (unsigned short*)smem;          // [64][136]
    float* pw = (float*)(smem + 64 * 136 * 2);
    int pb = bx - 256;
    int bj = pb >> 1, hb = pb & 1;
    int b = bj >> 7, j = bj & 127;

    {
        int half = lane >> 5, c4 = (lane & 31) * 4;
        #pragma unroll
        for (int it = 0; it < 8; it++) {
            int row = 16 * w + 2 * it + half;
            float4 v = *(const float4*)(e + (((size_t)b * 128 + hb * 64 + row) * 128 + j) * 128 + c4);
            unsigned* dst = (unsigned*)&Ab[row * 136 + c4];
            dst[0] = pack2(v.x, v.y);
            dst[1] = pack2(v.z, v.w);
        }
    }
    __builtin_amdgcn_wave_barrier();

    f32x4 acc[8];
    #pragma unroll
    for (int t = 0; t < 8; t++) acc[t] = 0.f;
    #pragma unroll
    for (int ks = 0; ks < 4; ks++) {
        int kf = ks * 32 + q * 8;
        short8 a0 = *(const short8*)&Ab[(16 * w + n) * 136 + kf];
        #pragma unroll
        for (int t = 0; t < 8; t++) {
            short8 bt = *(const short8*)&prep[WMET_OFF + ((ks * 8 + t) * 64 + lane) * 8];
            acc[t] = MFMA16(a0, bt, acc[t]);
        }
    }

    float msum[8];
    #pragma unroll
    for (int t = 0; t < 8; t++)
        msum[t] = ws[MSG1 + (size_t)bj * 128 + 16 * t + n] + ws[MSGG + (size_t)b * 128 + 16 * t + n];
    float adjm[4];
    float rs[4], rss[4];
    #pragma unroll
    for (int reg = 0; reg < 4; reg++) {
        int gi = hb * 64 + 16 * w + 4 * q + reg;
        bool av = rdbool(adj, ((size_t)b * 128 + gi) * 128 + j, isInt);
        adjm[reg] = av ? 1.f : 0.f;
        float s = 0.f, ssq = 0.f;
        #pragma unroll
        for (int t = 0; t < 8; t++) {
            float v = acc[t][reg] * adjm[reg]
                    + ws[MSG2 + ((size_t)b * 128 + gi) * 128 + 16 * t + n] + msum[t];
            acc[t][reg] = v;
            s += v; ssq += v * v;
        }
        rs[reg] = s; rss[reg] = ssq;
    }
    #pragma unroll
    for (int d = 1; d < 16; d <<= 1) {
        #pragma unroll
        for (int reg = 0; reg < 4; reg++) {
            rs[reg]  += __shfl_xor(rs[reg], d, 64);
            rss[reg] += __shfl_xor(rss[reg], d, 64);
        }
    }
    {
        float s1v[8], o1v[8];
        #pragma unroll
        for (int t = 0; t < 8; t++) { s1v[t] = ln1s[16 * t + n]; o1v[t] = ln1o[16 * t + n]; }
        #pragma unroll
        for (int reg = 0; reg < 4; reg++) {
            float mu = rs[reg] * (1.f / 128);
            float inv = rsqrtf(rss[reg] * (1.f / 128) - mu * mu + EPSF);
            int row = 16 * w + 4 * q + reg;
            #pragma unroll
            for (int t = 0; t < 8; t++) {
                float v = fmaxf(s1v[t] * inv * (acc[t][reg] - mu) + o1v[t], 0.f);
                Ab[row * 136 + 16 * t + n] = f2bf(v);
            }
        }
    }
    __builtin_amdgcn_wave_barrier();

    #pragma unroll
    for (int t = 0; t < 8; t++) acc[t] = 0.f;
    #pragma unroll
    for (int ks = 0; ks < 4; ks++) {
        int kf = ks * 32 + q * 8;
        short8 a0 = *(const short8*)&Ab[(16 * w + n) * 136 + kf];
        #pragma unroll
        for (int t = 0; t < 8; t++) {
            short8 bt = *(const short8*)&prep[W1T_OFF + ((ks * 8 + t) * 64 + lane) * 8];
            acc[t] = MFMA16(a0, bt, acc[t]);
        }
    }
    #pragma unroll
    for (int reg = 0; reg < 4; reg++) {
        float s = 0.f, ssq = 0.f;
        #pragma unroll
        for (int t = 0; t < 8; t++) { float v = acc[t][reg]; s += v; ssq += v * v; }
        rs[reg] = s; rss[reg] = ssq;
    }
    #pragma unroll
    for (int d = 1; d < 16; d <<= 1) {
        #pragma unroll
        for (int reg = 0; reg < 4; reg++) {
            rs[reg]  += __shfl_xor(rs[reg], d, 64);
            rss[reg] += __shfl_xor(rss[reg], d, 64);
        }
    }
    {
        float s2v[8], o2v[8];
        #pragma unroll
        for (int t = 0; t < 8; t++) { s2v[t] = ln2s[16 * t + n]; o2v[t] = ln2o[16 * t + n]; }
        #pragma unroll
        for (int reg = 0; reg < 4; reg++) {
            float mu = rs[reg] * (1.f / 128);
            float inv = rsqrtf(rss[reg] * (1.f / 128) - mu * mu + EPSF);
            int row = 16 * w + 4 * q + reg;
            #pragma unroll
            for (int t = 0; t < 8; t++) {
                float v = fmaxf(s2v[t] * inv * (acc[t][reg] - mu) + o2v[t], 0.f);
                Ab[row * 136 + 16 * t + n] = f2bf(v);
            }
        }
    }
    __builtin_amdgcn_wave_barrier();

    #pragma unroll
    for (int t = 0; t < 8; t++) acc[t] = 0.f;
    #pragma unroll
    for (int ks = 0; ks < 4; ks++) {
        int kf = ks * 32 + q * 8;
        short8 a0 = *(const short8*)&Ab[(16 * w + n) * 136 + kf];
        #pragma unroll
        for (int t = 0; t < 8; t++) {
            short8 bt = *(const short8*)&prep[W2T_OFF + ((ks * 8 + t) * 64 + lane) * 8];
            acc[t] = MFMA16(a0, bt, acc[t]);
        }
    }
    float colmax[8];
    #pragma unroll
    for (int t = 0; t < 8; t++) colmax[t] = NEGF;
    #pragma unroll
    for (int reg = 0; reg < 4; reg++) {
        if (adjm[reg] > 0.f) {
            #pragma unroll
            for (int t = 0; t < 8; t++) colmax[t] = fmaxf(colmax[t], acc[t][reg]);
        }
    }
    #pragma unroll
    for (int t = 0; t < 8; t++) {
        colmax[t] = fmaxf(colmax[t], __shfl_xor(colmax[t], 16, 64));
        colmax[t] = fmaxf(colmax[t], __shfl_xor(colmax[t], 32, 64));
    }
    if (lane < 16) {
        #pragma unroll
        for (int t = 0; t < 8; t++) pw[w * 128 + 16 * t + lane] = colmax[t];
    }
    __syncthreads();
    if (tid < 128) {
        float mx = fmaxf(fmaxf(pw[tid], pw[128 + tid]), fmaxf(pw[256 + tid], pw[384 + tid]));
        ws[PM0 + (size_t)hb * 65536 + (size_t)bj * 128 + tid] = mx;
    }
}

// ============================================================
// K3: combine pair halves -> msgs; ret = LN(z@WU1 + msgs@WU2). grid 512, block 128
// ============================================================
__global__ __launch_bounds__(128) void k_final(
    const float* __restrict__ ws, const float* __restrict__ WU2,
    const float* __restrict__ lnfs, const float* __restrict__ lnfo,
    float* __restrict__ out)
{
    int bn = blockIdx.x, tid = threadIdx.x;
    __shared__ float mrow[128];
    __shared__ float red[4];
    float mx = fmaxf(ws[PM0 + (size_t)bn * 128 + tid], ws[PM0 + 65536 + (size_t)bn * 128 + tid]);
    mrow[tid] = mx;
    out[O_MSG + (size_t)bn * 128 + tid] = mx;
    __syncthreads();
    float y = ws[ZWU1 + (size_t)bn * 128 + tid];
    float a0 = 0.f, a1 = 0.f;
    #pragma unroll 8
    for (int k = 0; k < 128; k += 2) {
        a0 = fmaf(mrow[k], WU2[k * 128 + tid], a0);
        a1 = fmaf(mrow[k + 1], WU2[(k + 1) * 128 + tid], a1);
    }
    y += a0 + a1;
    float s = y, ss = y * y;
    for (int d = 1; d < 64; d <<= 1) { s += __shfl_xor(s, d, 64); ss += __shfl_xor(ss, d, 64); }
    if ((tid & 63) == 0) { red[(tid >> 6) * 2] = s; red[(tid >> 6) * 2 + 1] = ss; }
    __syncthreads();
    float S = red[0] + red[2], SS = red[1] + red[3];
    float m_ = S * (1.f / 128), v_ = SS * (1.f / 128) - m_ * m_;
    float r = rsqrtf(v_ + EPSF);
    out[O_RET + (size_t)bn * 128 + tid] = lnfs[tid] * r * (y - m_) + lnfo[tid];
}

// ============================================================
extern "C" void kernel_launch(void* const* d_in, const int* in_sizes, int n_in,
                              void* d_out, int out_size, void* d_ws, size_t ws_size,
                              hipStream_t stream)
{
    const float* z    = (const float*)d_in[0];
    const float* e    = (const float*)d_in[1];
    const float* gf   = (const float*)d_in[2];
    const void*  mask = d_in[3];
    const void*  adj  = d_in[4];
    const float* Wt1 = (const float*)d_in[5];
    const float* Wt2 = (const float*)d_in[6];
    const float* Wt3 = (const float*)d_in[7];
    const float* We1 = (const float*)d_in[8];
    const float* We2 = (const float*)d_in[9];
    const float* We3 = (const float*)d_in[10];
    const float* Wg  = (const float*)d_in[11];
    const float* Wm1 = (const float*)d_in[12];
    const float* Wm2 = (const float*)d_in[13];
    const float* Wme = (const float*)d_in[14];
    const float* Wmg = (const float*)d_in[15];
    const float* ln1s = (const float*)d_in[16];
    const float* ln1o = (const float*)d_in[17];
    const float* W1   = (const float*)d_in[18];
    const float* ln2s = (const float*)d_in[19];
    const float* ln2o = (const float*)d_in[20];
    const float* W2   = (const float*)d_in[21];
    const float* WU1  = (const float*)d_in[22];
    const float* WU2  = (const float*)d_in[23];
    const float* WU3  = (const float*)d_in[24];
    const float* lnfs = (const float*)d_in[25];
    const float* lnfo = (const float*)d_in[26];
    float* out = (float*)d_out;
    float* ws  = (float*)d_ws;
    unsigned short* prep = (unsigned short*)(ws + PREPF);

    hipLaunchKernelGGL(k_pre, dim3(1220), dim3(256), 0, stream,
                       z, e, mask, Wt1, Wt2, Wt3, Wm1, Wm2, WU1, gf, Wg, Wmg,
                       W1, W2, Wme, We1, We2, We3, ws, prep);
    hipLaunchKernelGGL(k_main, dim3(1280), dim3(256), 0, stream,
                       e, mask, adj, ln1s, ln1o, ln2s, ln2o, prep, WU3, ws, out);
    hipLaunchKernelGGL(k_final, dim3(512), dim3(128), 0, stream,
                       ws, WU2, lnfs, lnfo, out);
}

// Round 2
// 180.724 us; speedup vs baseline: 1.0673x; 1.0667x over previous
//
#include <hip/hip_runtime.h>

// Problem constants
#define BN   4
#define NN   128
#define INF  256
#define EF   128
#define OUTF 128
#define EPSF 1e-5f
#define NEGF -998244352.0f   // bf16(1e9); matches the bf16-rounded np reference

typedef __attribute__((ext_vector_type(8))) short short8;
typedef __attribute__((ext_vector_type(4))) float f32x4;

#define MFMA16(a, b, c) __builtin_amdgcn_mfma_f32_16x16x32_bf16(a, b, c, 0, 0, 0)

__device__ __forceinline__ unsigned short f2bf(float f) {
    unsigned u = __float_as_uint(f);
    u += 0x7fffu + ((u >> 16) & 1u);
    return (unsigned short)(u >> 16);
}
__device__ __forceinline__ unsigned pack2(float a, float b) {
    return (unsigned)f2bf(a) | ((unsigned)f2bf(b) << 16);
}

// ---- workspace layout (float offsets) ----
constexpr size_t TRI1 = 0;            // B*N*8   tri_1 (masked)  [folded into E1T; kept]
constexpr size_t TRI2 = 4096;
constexpr size_t TRI3 = 8192;
constexpr size_t MSG1 = 12288;        // B*N*128 msg_1 (masked)
constexpr size_t MSG2 = 77824;
constexpr size_t ZWU1 = 143360;
constexpr size_t TRIG = 208896;       // B*8
constexpr size_t MSGG = 209920;       // B*128
constexpr size_t E1T  = 210944;       // B*N*N*8  fp32 [b][j][i][c]  (tri_e1 + tri_1 folded)
constexpr size_t E2T  = 735232;       // B*N*N*8  fp32 [b][k][i][c]
constexpr size_t E3N  = 1259520;      // B*N*N*8  fp32 [b][j][k][c]
constexpr size_t PREPF = 1914880;     // bf16 prepped weights (ushort region)

// prep (ushort units), MFMA-fragment order:
// ((ks*8 + t)*64 + lane)*8 + jj == W^T[16t + (lane&15)][ks*32 + (lane>>4)*8 + jj]
constexpr int W1T_OFF  = 0;
constexpr int W2T_OFF  = 16384;
constexpr int WMET_OFF = 32768;

// ---- output layout (float offsets): ret, msgs, tri_msgs ----
constexpr size_t O_RET = 0;
constexpr size_t O_MSG = 65536;
constexpr size_t O_TRI = 131072;

__device__ __forceinline__ int detect_int(const void* mask) {
    const unsigned char* m = (const unsigned char*)mask;
    return (m[1] | m[2] | m[3]) == 0 ? 1 : 0;
}
__device__ __forceinline__ bool rdbool(const void* p, size_t idx, int isInt) {
    if (isInt) return ((const int*)p)[idx] != 0;
    return ((const unsigned char*)p)[idx] != 0;
}

// ============================================================
// K1: tri-e projection (0..511, full 128-row blocks) + z proj (512..1023)
//     + graph (1024..1027) + weight prep (1028..1219).  256 thr.
// ============================================================
__global__ __launch_bounds__(256, 4) void k_pre(
    const float* __restrict__ z, const float* __restrict__ e, const void* __restrict__ mask,
    const float* __restrict__ Wt1, const float* __restrict__ Wt2, const float* __restrict__ Wt3,
    const float* __restrict__ Wm1, const float* __restrict__ Wm2, const float* __restrict__ WU1,
    const float* __restrict__ g, const float* __restrict__ Wg, const float* __restrict__ Wmg,
    const float* __restrict__ W1, const float* __restrict__ W2, const float* __restrict__ Wme,
    const float* __restrict__ We1, const float* __restrict__ We2, const float* __restrict__ We3,
    float* __restrict__ ws, unsigned short* __restrict__ prep)
{
    int bx = blockIdx.x, tid = threadIdx.x;
    __shared__ __align__(16) unsigned char smem[128 * 136 * 2];

    if (bx < 512) {
        // ---------- tri-e projection: block = one (b,i) ----------
        unsigned short* Ab = (unsigned short*)smem;
        int bi = bx;
        int b = bi >> 7, i = bi & 127;
        int lane = tid & 63, w = tid >> 6, q = lane >> 4, n = lane & 15;
        {
            int half = lane >> 5, c4 = (lane & 31) * 4;
            #pragma unroll
            for (int it = 0; it < 16; it++) {
                int row = 32 * w + 2 * it + half;
                float4 v = *(const float4*)(e + (size_t)bi * 16384 + (size_t)row * 128 + c4);
                unsigned* dst = (unsigned*)&Ab[row * 136 + c4];
                dst[0] = pack2(v.x, v.y);
                dst[1] = pack2(v.z, v.w);
            }
        }
        // t1 row for node i: masked z[b,i,:]@Wt1, per-wave redundant.
        float t1v;
        {
            int c = lane & 7, kk = lane >> 3;   // kk in 0..7, 32-k chunks
            const float* zr = z + (size_t)bi * INF;
            float s = 0.f;
            #pragma unroll
            for (int m = 0; m < 32; m++) s = fmaf(zr[kk * 32 + m], Wt1[(kk * 32 + m) * 8 + c], s);
            s += __shfl_xor(s, 8, 64);
            s += __shfl_xor(s, 16, 64);
            s += __shfl_xor(s, 32, 64);
            int isInt = detect_int(mask);
            t1v = rdbool(mask, bi, isInt) ? s : 0.f;
        }
        // gather packed-We B fragments (cols: We1|We2|We3|0), L1-hot 4KB arrays
        short8 bfrag[4][2];
        {
            #pragma unroll
            for (int t = 0; t < 2; t++) {
                int col = 16 * t + n;
                const float* Wsel = (col < 8) ? We1 : (col < 16 ? We2 : We3);
                int csel = col & 7;
                float mval = (col < 24) ? 1.f : 0.f;
                #pragma unroll
                for (int ks = 0; ks < 4; ks++) {
                    union { short8 s; unsigned short u[8]; } tmp;
                    #pragma unroll
                    for (int jj = 0; jj < 8; jj++) {
                        int k = ks * 32 + q * 8 + jj;
                        tmp.u[jj] = f2bf(Wsel[k * 8 + csel] * mval);
                    }
                    bfrag[ks][t] = tmp.s;
                }
            }
        }
        __builtin_amdgcn_wave_barrier();

        f32x4 ac2[2][2];
        #pragma unroll
        for (int rt = 0; rt < 2; rt++)
            #pragma unroll
            for (int t = 0; t < 2; t++) ac2[rt][t] = 0.f;
        #pragma unroll
        for (int ks = 0; ks < 4; ks++) {
            int k0 = ks * 32 + q * 8;
            short8 a0 = *(const short8*)&Ab[(32 * w + n) * 136 + k0];
            short8 a1 = *(const short8*)&Ab[(32 * w + 16 + n) * 136 + k0];
            #pragma unroll
            for (int t = 0; t < 2; t++) {
                ac2[0][t] = MFMA16(a0, bfrag[ks][t], ac2[0][t]);
                ac2[1][t] = MFMA16(a1, bfrag[ks][t], ac2[1][t]);
            }
        }
        #pragma unroll
        for (int rt = 0; rt < 2; rt++)
            #pragma unroll
            for (int reg = 0; reg < 4; reg++) {
                int row = 32 * w + 16 * rt + 4 * q + reg;
                float v0 = ac2[rt][0][reg];
                if (n < 8) ws[E1T + ((size_t)(b * 128 + row) * 128 + i) * 8 + n] = v0 + t1v;
                else       ws[E2T + ((size_t)(b * 128 + row) * 128 + i) * 8 + (n - 8)] = v0;
                if (n < 8) ws[E3N + ((size_t)bi * 128 + row) * 8 + n] = ac2[rt][1][reg];
            }
        return;
    }
    if (bx < 1024) {
        // ---------- z-row projections (2-way split accumulators for ILP) ----------
        int bn = bx - 512;
        int isInt = detect_int(mask);
        float* zr = (float*)smem;
        zr[tid] = z[(size_t)bn * INF + tid];
        __syncthreads();
        float mk = rdbool(mask, bn, isInt) ? 1.f : 0.f;
        for (int idx = tid; idx < 408; idx += 256) {
            const float* W; int c; size_t dst; int width; bool msk;
            if (idx < 8)        { W = Wt1; c = idx;       dst = TRI1 + (size_t)bn * 8;   width = 8;   msk = true;  }
            else if (idx < 16)  { W = Wt2; c = idx - 8;   dst = TRI2 + (size_t)bn * 8;   width = 8;   msk = true;  }
            else if (idx < 24)  { W = Wt3; c = idx - 16;  dst = TRI3 + (size_t)bn * 8;   width = 8;   msk = true;  }
            else if (idx < 152) { W = Wm1; c = idx - 24;  dst = MSG1 + (size_t)bn * 128; width = 128; msk = true;  }
            else if (idx < 280) { W = Wm2; c = idx - 152; dst = MSG2 + (size_t)bn * 128; width = 128; msk = true;  }
            else                { W = WU1; c = idx - 280; dst = ZWU1 + (size_t)bn * 128; width = 128; msk = false; }
            float a0 = 0.f, a1 = 0.f;
            #pragma unroll 8
            for (int k = 0; k < INF; k += 2) {
                a0 += zr[k] * W[k * width + c];
                a1 += zr[k + 1] * W[(k + 1) * width + c];
            }
            float acc = a0 + a1;
            ws[dst + c] = msk ? acc * mk : acc;
        }
        return;
    }
    if (bx < 1028) {
        // ---------- graph_fts projections ----------
        int b = bx - 1024;
        float* gr = (float*)smem;
        if (tid < 128) gr[tid] = g[b * 128 + tid];
        __syncthreads();
        if (tid < 8) {
            float a = 0.f;
            for (int k = 0; k < 128; k++) a += gr[k] * Wg[k * 8 + tid];
            ws[TRIG + b * 8 + tid] = a;
        } else if (tid >= 128) {
            int c = tid - 128;
            float a = 0.f;
            for (int k = 0; k < 128; k++) a += gr[k] * Wmg[k * 128 + c];
            ws[MSGG + b * 128 + c] = a;
        }
        return;
    }
    // ---------- weight prep (fragment-order), W1/W2/Wme only ----------
    {
        int idx = (bx - 1028) * 256 + tid;   // < 49152
        const float* W = (idx < 16384) ? W1 : (idx < 32768 ? W2 : Wme);
        int local = idx & 16383;
        int f = local >> 3, jj = local & 7;
        int lane = f & 63, fg = f >> 6;
        int t = fg & 7, ks = fg >> 3;
        int n = lane & 15, q = lane >> 4;
        int row = 16 * t + n;
        int k = ks * 32 + q * 8 + jj;
        prep[idx] = f2bf(W[k * 128 + row]);
    }
}

// ============================================================
// K2: bx<256 triplet pooling, bx>=256 pair-MLP full blocks (32 rows/wave).
// grid 768, block 256.
//
// Pair: register double-buffered bt prefetch (btc/btn) so the 96 L2 b128
// prep loads per wave overlap MFMA instead of serializing (r1 postmortem:
// VGPR=60 meant compiler kept ~1 bt in flight -> ~15K cyc exposed latency).
// launch_bounds (256,3) gives the allocator ~170 VGPRs for acc[2][8]+2 bufs.
// Mask is contiguous (arange<len): blocks with j>=len write NEGF and exit;
// waves with 32w>=len skip compute. Triplet: needU tiles (both j,k ranges
// past len) are rare -> fast single-accumulator branchless path otherwise.
// ============================================================
#define PAIR_GEMM(OFF) do {                                                            \
    short8 btc[8], btn[8];                                                             \
    _Pragma("unroll")                                                                  \
    for (int t = 0; t < 8; t++)                                                        \
        btc[t] = *(const short8*)&prep[(OFF) + ((0 * 8 + t) * 64 + lane) * 8];         \
    _Pragma("unroll")                                                                  \
    for (int ks = 0; ks < 4; ks++) {                                                   \
        int kf = ks * 32 + q * 8;                                                      \
        short8 a0 = *(const short8*)&Ab[(32 * w + n) * 136 + kf];                      \
        short8 a1 = *(const short8*)&Ab[(32 * w + 16 + n) * 136 + kf];                 \
        if (ks < 3) {                                                                  \
            _Pragma("unroll")                                                          \
            for (int t = 0; t < 8; t++)                                                \
                btn[t] = *(const short8*)&prep[(OFF) + (((ks + 1) * 8 + t) * 64 + lane) * 8]; \
        }                                                                              \
        _Pragma("unroll")                                                              \
        for (int t = 0; t < 8; t++) {                                                  \
            acc[0][t] = MFMA16(a0, btc[t], acc[0][t]);                                 \
            acc[1][t] = MFMA16(a1, btc[t], acc[1][t]);                                 \
        }                                                                              \
        if (ks < 3) {                                                                  \
            _Pragma("unroll")                                                          \
            for (int t = 0; t < 8; t++) btc[t] = btn[t];                               \
        }                                                                              \
    }                                                                                  \
} while (0)

__global__ __launch_bounds__(256, 3) void k_main(
    const float* __restrict__ e, const void* __restrict__ mask, const void* __restrict__ adj,
    const float* __restrict__ ln1s, const float* __restrict__ ln1o,
    const float* __restrict__ ln2s, const float* __restrict__ ln2o,
    const unsigned short* __restrict__ prep, const float* __restrict__ WU3,
    float* __restrict__ ws, float* __restrict__ out)
{
    int bx = blockIdx.x, tid = threadIdx.x;
    __shared__ __align__(16) unsigned char smem[128 * 136 * 2 + 2048];
    int lane = tid & 63, w = tid >> 6, q = lane >> 4, n = lane & 15;
    int isInt = detect_int(mask);

    if (bx < 256) {
        // ================= triplet max-plus pooling =================
        int g = bx;
        int j0 = ((g >> 3) & 7) * 16, k0 = (g & 7) * 16, b = g >> 6;
        int wi = w >> 1, wc = w & 1;          // i-half, channel-half
        int tj = lane >> 3, tk = lane & 7;    // 8x8 lanes; outputs (tj,tj+8)x(tk,tk+8)
        int col4 = (tid & 31) * 4, rowgrp = tid >> 5;

        int lenb;
        {
            unsigned long long m0 = __ballot(rdbool(mask, (size_t)b * 128 + lane, isInt));
            unsigned long long m1 = __ballot(rdbool(mask, (size_t)b * 128 + 64 + lane, isInt));
            lenb = __popcll(m0) + __popcll(m1);
        }
        bool needU = (j0 + 15 >= lenb) && (k0 + 15 >= lenb);

        // wave-private staging: P[16][8ii][4c]+pad and Q, stride 36 words
        float* Pb = (float*)smem + w * 1152;
        float* Qb = Pb + 576;

        f32x4 aM[2][2];
        #pragma unroll
        for (int jj = 0; jj < 2; jj++)
            #pragma unroll
            for (int kk = 0; kk < 2; kk++) aM[jj][kk] = NEGF;

        if (!needU) {
            // fast path: every output has mj|mk true -> max over ALL i, one acc set
            for (int ch = 0; ch < 8; ch++) {
                int ibase = wi * 64 + ch * 8;
                #pragma unroll
                for (int r = 0; r < 2; r++) {
                    int f = r * 64 + lane;
                    int jr = f >> 3, ii = f & 7;
                    f32x4 pv = *(const f32x4*)(ws + E1T + (size_t)(b * 128 + j0 + jr) * 1024 + (ibase + ii) * 8 + wc * 4);
                    f32x4 qv = *(const f32x4*)(ws + E2T + (size_t)(b * 128 + k0 + jr) * 1024 + (ibase + ii) * 8 + wc * 4);
                    *(f32x4*)(Pb + jr * 36 + ii * 4) = pv;
                    *(f32x4*)(Qb + jr * 36 + ii * 4) = qv;
                }
                __builtin_amdgcn_wave_barrier();
                #pragma unroll
                for (int ii = 0; ii < 8; ii++) {
                    f32x4 p0 = *(const f32x4*)(Pb + tj * 36 + ii * 4);
                    f32x4 p1 = *(const f32x4*)(Pb + (tj + 8) * 36 + ii * 4);
                    f32x4 q0 = *(const f32x4*)(Qb + tk * 36 + ii * 4);
                    f32x4 q1 = *(const f32x4*)(Qb + (tk + 8) * 36 + ii * 4);
                    aM[0][0] = __builtin_elementwise_max(aM[0][0], p0 + q0);
                    aM[0][1] = __builtin_elementwise_max(aM[0][1], p0 + q1);
                    aM[1][0] = __builtin_elementwise_max(aM[1][0], p1 + q0);
                    aM[1][1] = __builtin_elementwise_max(aM[1][1], p1 + q1);
                }
            }
        } else {
            f32x4 aU[2][2];
            #pragma unroll
            for (int jj = 0; jj < 2; jj++)
                #pragma unroll
                for (int kk = 0; kk < 2; kk++) aU[jj][kk] = NEGF;
            unsigned long long mball = __ballot(rdbool(mask, (size_t)b * 128 + wi * 64 + lane, isInt));
            for (int ch = 0; ch < 8; ch++) {
                int ibase = wi * 64 + ch * 8;
                #pragma unroll
                for (int r = 0; r < 2; r++) {
                    int f = r * 64 + lane;
                    int jr = f >> 3, ii = f & 7;
                    f32x4 pv = *(const f32x4*)(ws + E1T + (size_t)(b * 128 + j0 + jr) * 1024 + (ibase + ii) * 8 + wc * 4);
                    f32x4 qv = *(const f32x4*)(ws + E2T + (size_t)(b * 128 + k0 + jr) * 1024 + (ibase + ii) * 8 + wc * 4);
                    *(f32x4*)(Pb + jr * 36 + ii * 4) = pv;
                    *(f32x4*)(Qb + jr * 36 + ii * 4) = qv;
                }
                __builtin_amdgcn_wave_barrier();
                #pragma unroll
                for (int ii = 0; ii < 8; ii++) {
                    f32x4 p0 = *(const f32x4*)(Pb + tj * 36 + ii * 4);
                    f32x4 p1 = *(const f32x4*)(Pb + (tj + 8) * 36 + ii * 4);
                    f32x4 q0 = *(const f32x4*)(Qb + tk * 36 + ii * 4);
                    f32x4 q1 = *(const f32x4*)(Qb + (tk + 8) * 36 + ii * 4);
                    f32x4 v00 = p0 + q0, v01 = p0 + q1, v10 = p1 + q0, v11 = p1 + q1;
                    if ((mball >> (ch * 8 + ii)) & 1) {
                        aM[0][0] = __builtin_elementwise_max(aM[0][0], v00);
                        aM[0][1] = __builtin_elementwise_max(aM[0][1], v01);
                        aM[1][0] = __builtin_elementwise_max(aM[1][0], v10);
                        aM[1][1] = __builtin_elementwise_max(aM[1][1], v11);
                    } else {
                        aU[0][0] = __builtin_elementwise_max(aU[0][0], v00);
                        aU[0][1] = __builtin_elementwise_max(aU[0][1], v01);
                        aU[1][0] = __builtin_elementwise_max(aU[1][0], v10);
                        aU[1][1] = __builtin_elementwise_max(aU[1][1], v11);
                    }
                }
            }
            // outputs with mj|mk include unmasked-i contributions too
            bool mj[2], mk2[2];
            mj[0]  = (j0 + tj)     < lenb;
            mj[1]  = (j0 + tj + 8) < lenb;
            mk2[0] = (k0 + tk)     < lenb;
            mk2[1] = (k0 + tk + 8) < lenb;
            #pragma unroll
            for (int jj = 0; jj < 2; jj++)
                #pragma unroll
                for (int kk = 0; kk < 2; kk++)
                    if (mj[jj] | mk2[kk])
                        aM[jj][kk] = __builtin_elementwise_max(aM[jj][kk], aU[jj][kk]);
        }
        __syncthreads();   // all staging reads done; alias staging region as 'pooled'
        float* pooled = (float*)smem;   // [8][260] c-major
        float4 wvr[8];
        #pragma unroll
        for (int c = 0; c < 8; c++) wvr[c] = *(const float4*)(WU3 + c * 128 + col4);

        if (wi == 0) {
            #pragma unroll
            for (int jj = 0; jj < 2; jj++)
                #pragma unroll
                for (int kk = 0; kk < 2; kk++) {
                    int p = (tj + 8 * jj) * 16 + (tk + 8 * kk);
                    #pragma unroll
                    for (int cc = 0; cc < 4; cc++)
                        pooled[(wc * 4 + cc) * 260 + p] = aM[jj][kk][cc];
                }
        }
        __syncthreads();
        if (wi == 1) {
            const float* tg = ws + TRIG + (size_t)b * 8 + wc * 4;
            #pragma unroll
            for (int jj = 0; jj < 2; jj++)
                #pragma unroll
                for (int kk = 0; kk < 2; kk++) {
                    int jv = j0 + tj + 8 * jj, kv = k0 + tk + 8 * kk;
                    const float* t2 = ws + TRI2 + (size_t)(b * 128 + jv) * 8 + wc * 4;
                    const float* t3 = ws + TRI3 + (size_t)(b * 128 + kv) * 8 + wc * 4;
                    const float* e3 = ws + E3N + ((size_t)(b * 128 + jv) * 128 + kv) * 8 + wc * 4;
                    int p = (tj + 8 * jj) * 16 + (tk + 8 * kk);
                    #pragma unroll
                    for (int cc = 0; cc < 4; cc++) {
                        int idx = (wc * 4 + cc) * 260 + p;
                        pooled[idx] = fmaxf(pooled[idx], aM[jj][kk][cc]) + t2[cc] + t3[cc] + e3[cc] + tg[cc];
                    }
                }
        }
        __syncthreads();
        // epilogue: relu(pooled @ WU3); pooled reads broadcast, no LDS weights
        #pragma unroll
        for (int pass = 0; pass < 32; pass++) {
            int p = pass * 8 + rowgrp;
            float4 s = { 0.f, 0.f, 0.f, 0.f };
            #pragma unroll
            for (int c = 0; c < 8; c++) {
                float pv = pooled[c * 260 + p];
                s.x += pv * wvr[c].x; s.y += pv * wvr[c].y;
                s.z += pv * wvr[c].z; s.w += pv * wvr[c].w;
            }
            s.x = fmaxf(s.x, 0.f); s.y = fmaxf(s.y, 0.f);
            s.z = fmaxf(s.z, 0.f); s.w = fmaxf(s.w, 0.f);
            int pj = p >> 4, pk = p & 15;
            *(float4*)(out + O_TRI + ((size_t)(b * 128 + j0 + pj) * 128 + (k0 + pk)) * 128 + col4) = s;
        }
        return;
    }

    // ================= pair MLP: block = one (b,j), 32 rows/wave =================
    unsigned short* Ab = (unsigned short*)smem;
    float* pw = (float*)(smem + 128 * 136 * 2);
    int bj = bx - 256;
    int b = bj >> 7, j = bj & 127;

    int lenb;
    {
        unsigned long long m0 = __ballot(rdbool(mask, (size_t)b * 128 + lane, isInt));
        unsigned long long m1 = __ballot(rdbool(mask, (size_t)b * 128 + 64 + lane, isInt));
        lenb = __popcll(m0) + __popcll(m1);
    }
    if (j >= lenb) {
        // adj column empty -> msgs row = NEGF exactly as the all-false colmax path
        if (tid < 128) out[O_MSG + (size_t)bj * 128 + tid] = NEGF;
        return;
    }

    float colmax[8];
    #pragma unroll
    for (int t = 0; t < 8; t++) colmax[t] = NEGF;

    bool waveActive = (32 * w) < lenb;
    if (waveActive) {
        {
            int half = lane >> 5, c4 = (lane & 31) * 4;
            #pragma unroll
            for (int it = 0; it < 16; it++) {
                int row = 32 * w + 2 * it + half;
                float4 v = *(const float4*)(e + (((size_t)b * 128 + row) * 128 + j) * 128 + c4);
                unsigned* dst = (unsigned*)&Ab[row * 136 + c4];
                dst[0] = pack2(v.x, v.y);
                dst[1] = pack2(v.z, v.w);
            }
        }
        __builtin_amdgcn_wave_barrier();

        f32x4 acc[2][8];
        #pragma unroll
        for (int rt = 0; rt < 2; rt++)
            #pragma unroll
            for (int t = 0; t < 8; t++) acc[rt][t] = 0.f;

        PAIR_GEMM(WMET_OFF);

        float msum[8];
        #pragma unroll
        for (int t = 0; t < 8; t++)
            msum[t] = ws[MSG1 + (size_t)bj * 128 + 16 * t + n] + ws[MSGG + (size_t)b * 128 + 16 * t + n];
        float adjm[2][4];
        float rs[2][4], rss[2][4];
        #pragma unroll
        for (int rt = 0; rt < 2; rt++)
            #pragma unroll
            for (int reg = 0; reg < 4; reg++) {
                int row = 32 * w + 16 * rt + 4 * q + reg;
                bool av = rdbool(adj, ((size_t)b * 128 + row) * 128 + j, isInt);
                adjm[rt][reg] = av ? 1.f : 0.f;
                float s = 0.f, ssq = 0.f;
                #pragma unroll
                for (int t = 0; t < 8; t++) {
                    float v = acc[rt][t][reg] * adjm[rt][reg]
                            + ws[MSG2 + ((size_t)b * 128 + row) * 128 + 16 * t + n] + msum[t];
                    acc[rt][t][reg] = v;
                    s += v; ssq += v * v;
                }
                rs[rt][reg] = s; rss[rt][reg] = ssq;
            }
        #pragma unroll
        for (int d = 1; d < 16; d <<= 1) {
            #pragma unroll
            for (int rt = 0; rt < 2; rt++)
                #pragma unroll
                for (int reg = 0; reg < 4; reg++) {
                    rs[rt][reg]  += __shfl_xor(rs[rt][reg], d, 64);
                    rss[rt][reg] += __shfl_xor(rss[rt][reg], d, 64);
                }
        }
        {
            float s1v[8], o1v[8];
            #pragma unroll
            for (int t = 0; t < 8; t++) { s1v[t] = ln1s[16 * t + n]; o1v[t] = ln1o[16 * t + n]; }
            #pragma unroll
            for (int rt = 0; rt < 2; rt++)
                #pragma unroll
                for (int reg = 0; reg < 4; reg++) {
                    float mu = rs[rt][reg] * (1.f / 128);
                    float inv = rsqrtf(rss[rt][reg] * (1.f / 128) - mu * mu + EPSF);
                    int row = 32 * w + 16 * rt + 4 * q + reg;
                    #pragma unroll
                    for (int t = 0; t < 8; t++) {
                        float v = fmaxf(s1v[t] * inv * (acc[rt][t][reg] - mu) + o1v[t], 0.f);
                        Ab[row * 136 + 16 * t + n] = f2bf(v);
                    }
                }
        }
        __builtin_amdgcn_wave_barrier();

        #pragma unroll
        for (int rt = 0; rt < 2; rt++)
            #pragma unroll
            for (int t = 0; t < 8; t++) acc[rt][t] = 0.f;
        PAIR_GEMM(W1T_OFF);
        #pragma unroll
        for (int rt = 0; rt < 2; rt++)
            #pragma unroll
            for (int reg = 0; reg < 4; reg++) {
                float s = 0.f, ssq = 0.f;
                #pragma unroll
                for (int t = 0; t < 8; t++) { float v = acc[rt][t][reg]; s += v; ssq += v * v; }
                rs[rt][reg] = s; rss[rt][reg] = ssq;
            }
        #pragma unroll
        for (int d = 1; d < 16; d <<= 1) {
            #pragma unroll
            for (int rt = 0; rt < 2; rt++)
                #pragma unroll
                for (int reg = 0; reg < 4; reg++) {
                    rs[rt][reg]  += __shfl_xor(rs[rt][reg], d, 64);
                    rss[rt][reg] += __shfl_xor(rss[rt][reg], d, 64);
                }
        }
        {
            float s2v[8], o2v[8];
            #pragma unroll
            for (int t = 0; t < 8; t++) { s2v[t] = ln2s[16 * t + n]; o2v[t] = ln2o[16 * t + n]; }
            #pragma unroll
            for (int rt = 0; rt < 2; rt++)
                #pragma unroll
                for (int reg = 0; reg < 4; reg++) {
                    float mu = rs[rt][reg] * (1.f / 128);
                    float inv = rsqrtf(rss[rt][reg] * (1.f / 128) - mu * mu + EPSF);
                    int row = 32 * w + 16 * rt + 4 * q + reg;
                    #pragma unroll
                    for (int t = 0; t < 8; t++) {
                        float v = fmaxf(s2v[t] * inv * (acc[rt][t][reg] - mu) + o2v[t], 0.f);
                        Ab[row * 136 + 16 * t + n] = f2bf(v);
                    }
                }
        }
        __builtin_amdgcn_wave_barrier();

        #pragma unroll
        for (int rt = 0; rt < 2; rt++)
            #pragma unroll
            for (int t = 0; t < 8; t++) acc[rt][t] = 0.f;
        PAIR_GEMM(W2T_OFF);

        #pragma unroll
        for (int rt = 0; rt < 2; rt++)
            #pragma unroll
            for (int reg = 0; reg < 4; reg++) {
                if (adjm[rt][reg] > 0.f) {
                    #pragma unroll
                    for (int t = 0; t < 8; t++) colmax[t] = fmaxf(colmax[t], acc[rt][t][reg]);
                }
            }
    }
    #pragma unroll
    for (int t = 0; t < 8; t++) {
        colmax[t] = fmaxf(colmax[t], __shfl_xor(colmax[t], 16, 64));
        colmax[t] = fmaxf(colmax[t], __shfl_xor(colmax[t], 32, 64));
    }
    if (lane < 16) {
        #pragma unroll
        for (int t = 0; t < 8; t++) pw[w * 128 + 16 * t + lane] = colmax[t];
    }
    __syncthreads();
    if (tid < 128) {
        float mx = fmaxf(fmaxf(pw[tid], pw[128 + tid]), fmaxf(pw[256 + tid], pw[384 + tid]));
        out[O_MSG + (size_t)bj * 128 + tid] = mx;
    }
}

// ============================================================
// K3: ret = LN(z@WU1 + msgs@WU2).  grid 512, block 128
// ============================================================
__global__ __launch_bounds__(128) void k_final(
    const float* __restrict__ ws, const float* __restrict__ WU2,
    const float* __restrict__ lnfs, const float* __restrict__ lnfo,
    float* __restrict__ out)
{
    int bn = blockIdx.x, tid = threadIdx.x;
    __shared__ float mrow[128];
    __shared__ float red[4];
    mrow[tid] = out[O_MSG + (size_t)bn * 128 + tid];
    __syncthreads();
    float y = ws[ZWU1 + (size_t)bn * 128 + tid];
    float a0 = 0.f, a1 = 0.f;
    #pragma unroll 8
    for (int k = 0; k < 128; k += 2) {
        a0 = fmaf(mrow[k], WU2[k * 128 + tid], a0);
        a1 = fmaf(mrow[k + 1], WU2[(k + 1) * 128 + tid], a1);
    }
    y += a0 + a1;
    float s = y, ss = y * y;
    for (int d = 1; d < 64; d <<= 1) { s += __shfl_xor(s, d, 64); ss += __shfl_xor(ss, d, 64); }
    if ((tid & 63) == 0) { red[(tid >> 6) * 2] = s; red[(tid >> 6) * 2 + 1] = ss; }
    __syncthreads();
    float S = red[0] + red[2], SS = red[1] + red[3];
    float m_ = S * (1.f / 128), v_ = SS * (1.f / 128) - m_ * m_;
    float r = rsqrtf(v_ + EPSF);
    out[O_RET + (size_t)bn * 128 + tid] = lnfs[tid] * r * (y - m_) + lnfo[tid];
}

// ============================================================
extern "C" void kernel_launch(void* const* d_in, const int* in_sizes, int n_in,
                              void* d_out, int out_size, void* d_ws, size_t ws_size,
                              hipStream_t stream)
{
    const float* z    = (const float*)d_in[0];
    const float* e    = (const float*)d_in[1];
    const float* gf   = (const float*)d_in[2];
    const void*  mask = d_in[3];
    const void*  adj  = d_in[4];
    const float* Wt1 = (const float*)d_in[5];
    const float* Wt2 = (const float*)d_in[6];
    const float* Wt3 = (const float*)d_in[7];
    const float* We1 = (const float*)d_in[8];
    const float* We2 = (const float*)d_in[9];
    const float* We3 = (const float*)d_in[10];
    const float* Wg  = (const float*)d_in[11];
    const float* Wm1 = (const float*)d_in[12];
    const float* Wm2 = (const float*)d_in[13];
    const float* Wme = (const float*)d_in[14];
    const float* Wmg = (const float*)d_in[15];
    const float* ln1s = (const float*)d_in[16];
    const float* ln1o = (const float*)d_in[17];
    const float* W1   = (const float*)d_in[18];
    const float* ln2s = (const float*)d_in[19];
    const float* ln2o = (const float*)d_in[20];
    const float* W2   = (const float*)d_in[21];
    const float* WU1  = (const float*)d_in[22];
    const float* WU2  = (const float*)d_in[23];
    const float* WU3  = (const float*)d_in[24];
    const float* lnfs = (const float*)d_in[25];
    const float* lnfo = (const float*)d_in[26];
    float* out = (float*)d_out;
    float* ws  = (float*)d_ws;
    unsigned short* prep = (unsigned short*)(ws + PREPF);

    hipLaunchKernelGGL(k_pre, dim3(1220), dim3(256), 0, stream,
                       z, e, mask, Wt1, Wt2, Wt3, Wm1, Wm2, WU1, gf, Wg, Wmg,
                       W1, W2, Wme, We1, We2, We3, ws, prep);
    hipLaunchKernelGGL(k_main, dim3(768), dim3(256), 0, stream,
                       e, mask, adj, ln1s, ln1o, ln2s, ln2o, prep, WU3, ws, out);
    hipLaunchKernelGGL(k_final, dim3(512), dim3(128), 0, stream,
                       ws, WU2, lnfs, lnfo, out);
}